// Round 1
// baseline (1986.686 us; speedup 1.0000x reference)
//
#include <hip/hip_runtime.h>
#include <cmath>

// ---------------------------------------------------------------------------
// PointCloudFeatureExtractor — full pipeline port (fp32).
// Stages: kNN(50) -> conv_surface -> conv_layer1 -> pool -> kNN -> conv2 ->
//         conv3 -> pool -> kNN -> conv4 -> global max -> FC.
// ---------------------------------------------------------------------------

__device__ __forceinline__ unsigned long long shfl_xor_u64(unsigned long long x, int mask) {
    unsigned int lo = (unsigned int)(x & 0xffffffffull);
    unsigned int hi = (unsigned int)(x >> 32);
    lo = __shfl_xor(lo, mask, 64);
    hi = __shfl_xor(hi, mask, 64);
    return (((unsigned long long)hi) << 32) | lo;
}

// kNN: one block (256 threads) per query row. Candidates = CPT*256.
// Selects SEL smallest distances (ties -> lower index, matching jax top_k),
// writes indices for iterations 1..SEL-1 (drops self / global min).
template <int CPT, int SEL>
__global__ __launch_bounds__(256) void knn_kernel(
    const float* __restrict__ v,   // (B, vStride, 3)
    int vStride,                   // batch row stride of v (=8192 always)
    int nRows,                     // query rows per batch
    int* __restrict__ outIdx)      // (B, nRows, SEL-1)
{
#pragma clang fp contract(off)
    const int tid  = threadIdx.x;
    const int bi   = blockIdx.x;          // b*nRows + row
    const int b    = bi / nRows;
    const int row  = bi % nRows;

    const float px = v[((size_t)b * vStride + row) * 3 + 0];
    const float py = v[((size_t)b * vStride + row) * 3 + 1];
    const float pz = v[((size_t)b * vStride + row) * 3 + 2];
    const float qrow = (px * px + py * py) + pz * pz;

    unsigned long long pk[CPT];
#pragma unroll
    for (int s = 0; s < CPT; ++s) {
        const int j = tid + (s << 8);
        const float cx = v[((size_t)b * vStride + j) * 3 + 0];
        const float cy = v[((size_t)b * vStride + j) * 3 + 1];
        const float cz = v[((size_t)b * vStride + j) * 3 + 2];
        const float inner = (px * cx + py * cy) + pz * cz;
        const float qc    = (cx * cx + cy * cy) + cz * cz;
        const float dist  = ((-2.0f * inner) + qc) + qrow;
        unsigned int u = __float_as_uint(dist);
        u = (u & 0x80000000u) ? ~u : (u | 0x80000000u);
        pk[s] = (((unsigned long long)u) << 32) | (unsigned int)j;
    }

    __shared__ unsigned long long red[4];
    __shared__ unsigned long long winner_s;
    const int lane = tid & 63;
    const int wid  = tid >> 6;

    for (int it = 0; it < SEL; ++it) {
        unsigned long long m = pk[0];
#pragma unroll
        for (int s = 1; s < CPT; ++s) m = (pk[s] < m) ? pk[s] : m;
#pragma unroll
        for (int off = 32; off > 0; off >>= 1) {
            unsigned long long o = shfl_xor_u64(m, off);
            m = (o < m) ? o : m;
        }
        if (lane == 0) red[wid] = m;
        __syncthreads();
        if (tid == 0) {
            unsigned long long a  = (red[0] < red[1]) ? red[0] : red[1];
            unsigned long long bb = (red[2] < red[3]) ? red[2] : red[3];
            winner_s = (a < bb) ? a : bb;
        }
        __syncthreads();
        const unsigned long long w = winner_s;
        const int widx = (int)(w & 0xffffffffull);
        if (it > 0 && tid == 0)
            outIdx[(size_t)bi * (SEL - 1) + (it - 1)] = widx;
        if ((widx & 255) == tid) {
            const int slot = widx >> 8;
#pragma unroll
            for (int s = 0; s < CPT; ++s)
                if (s == slot) pk[s] = ~0ull;
        }
        // no extra barrier needed: next red[] write happens after this
        // iteration's second barrier; winner_s rewritten only after the
        // next first barrier.
    }
}

// Unified conv: if fout==nullptr this is conv_surface (f_support=1, f_center=0).
// Block per vertex; NN neighbor unit directions staged in LDS; threads own
// output channels.
template <int NT>
__global__ __launch_bounds__(NT) void conv_kernel(
    const int*   __restrict__ idx,   // (B, V, NN)
    const float* __restrict__ v,     // (B, vStride, 3)
    int vStride, int V, int NN,
    const float* __restrict__ fout,  // (B, V, 2*oc) or nullptr
    int oc,
    const float* __restrict__ dirs,  // (3, oc)
    float* __restrict__ out,         // (B, V, oc)
    int do_relu)
{
#pragma clang fp contract(off)
    __shared__ float dnx[64], dny[64], dnz[64];
    __shared__ int   nb[64];
    const int bi  = blockIdx.x;     // b*V + i
    const int b   = bi / V;
    const int i   = bi % V;
    const int tid = threadIdx.x;

    if (tid < NN) {
        const int j = idx[(size_t)bi * NN + tid];
        nb[tid] = j;
        const float px = v[((size_t)b * vStride + i) * 3 + 0];
        const float py = v[((size_t)b * vStride + i) * 3 + 1];
        const float pz = v[((size_t)b * vStride + i) * 3 + 2];
        const float dx = v[((size_t)b * vStride + j) * 3 + 0] - px;
        const float dy = v[((size_t)b * vStride + j) * 3 + 1] - py;
        const float dz = v[((size_t)b * vStride + j) * 3 + 2] - pz;
        const float n  = sqrtf((dx * dx + dy * dy) + dz * dz);
        const float dn = fmaxf(n, 1e-12f);
        dnx[tid] = dx / dn;
        dny[tid] = dy / dn;
        dnz[tid] = dz / dn;
    }
    __syncthreads();

    for (int c = tid; c < oc; c += NT) {
        float d0 = dirs[c], d1 = dirs[oc + c], d2 = dirs[2 * oc + c];
        const float nd = sqrtf((d0 * d0 + d1 * d1) + d2 * d2);
        const float dc = fmaxf(nd, 1e-12f);
        d0 /= dc; d1 /= dc; d2 /= dc;

        float fcen = 0.f;
        if (fout) fcen = fout[(size_t)bi * (2 * oc) + c];

        float m = -INFINITY;
        for (int n = 0; n < NN; ++n) {
            float th = (dnx[n] * d0 + dny[n] * d1) + dnz[n] * d2;
            th = fmaxf(th, 0.f);
            float fs = 1.f;
            if (fout) fs = fout[((size_t)b * V + nb[n]) * (2 * oc) + oc + c];
            m = fmaxf(m, th * fs);
        }
        float r = fcen + m;
        if (do_relu) r = fmaxf(r, 0.f);
        out[(size_t)bi * oc + c] = r;
    }
}

// out(row, C) = A(row, ic) @ W(ic, C) + bias(C). Block per row.
__global__ __launch_bounds__(256) void gemm_bias(
    const float* __restrict__ A, const float* __restrict__ W,
    const float* __restrict__ bias, float* __restrict__ out,
    int ic, int C)
{
    __shared__ float arow[256];
    const int row = blockIdx.x;
    const int tid = threadIdx.x;
    for (int k = tid; k < ic; k += 256) arow[k] = A[(size_t)row * ic + k];
    __syncthreads();
    for (int c = tid; c < C; c += 256) {
        float acc = bias[c];
        for (int k = 0; k < ic; ++k) acc += arow[k] * W[(size_t)k * C + c];
        out[(size_t)row * C + c] = acc;
    }
}

// pooled[b,i,c] = max over 4 neighbors of fm[b, idx4[b,i,n], c]
__global__ __launch_bounds__(256) void pool_max(
    const int* __restrict__ idx4, const float* __restrict__ fm,
    int Vin, int pn, int C, float* __restrict__ out)
{
    const int bi  = blockIdx.x;      // b*pn + i
    const int b   = bi / pn;
    const int tid = threadIdx.x;
    const int j0 = idx4[(size_t)bi * 4 + 0];
    const int j1 = idx4[(size_t)bi * 4 + 1];
    const int j2 = idx4[(size_t)bi * 4 + 2];
    const int j3 = idx4[(size_t)bi * 4 + 3];
    for (int c = tid; c < C; c += 256) {
        float m = fm[((size_t)b * Vin + j0) * C + c];
        m = fmaxf(m, fm[((size_t)b * Vin + j1) * C + c]);
        m = fmaxf(m, fm[((size_t)b * Vin + j2) * C + c]);
        m = fmaxf(m, fm[((size_t)b * Vin + j3) * C + c]);
        out[(size_t)bi * C + c] = m;
    }
}

// feat[b,c] = max over V rows of fm[b,:,c]
__global__ __launch_bounds__(256) void colmax(
    const float* __restrict__ fm, int V, int C, float* __restrict__ out)
{
    const int b = blockIdx.y;
    const int c = blockIdx.x * 256 + threadIdx.x;
    if (c >= C) return;
    float m = -INFINITY;
    for (int i = 0; i < V; ++i) m = fmaxf(m, fm[((size_t)b * V + i) * C + c]);
    out[(size_t)b * C + c] = m;
}

// out[b, :256] = feat[b, :1024] @ W(1024,256) + bias
__global__ __launch_bounds__(256) void fc_kernel(
    const float* __restrict__ feat, const float* __restrict__ W,
    const float* __restrict__ bias, float* __restrict__ out)
{
    __shared__ float f[1024];
    const int b = blockIdx.x, tid = threadIdx.x;
    for (int k = tid; k < 1024; k += 256) f[k] = feat[(size_t)b * 1024 + k];
    __syncthreads();
    float acc = bias[tid];
    for (int k = 0; k < 1024; ++k) acc += f[k] * W[(size_t)k * 256 + tid];
    out[(size_t)b * 256 + tid] = acc;
}

extern "C" void kernel_launch(void* const* d_in, const int* in_sizes, int n_in,
                              void* d_out, int out_size, void* d_ws, size_t ws_size,
                              hipStream_t stream) {
    const float* verts = (const float*)d_in[0];
    const float* dir0  = (const float*)d_in[1];
    const float* w1 = (const float*)d_in[2];
    const float* b1 = (const float*)d_in[3];
    const float* d1 = (const float*)d_in[4];
    const float* w2 = (const float*)d_in[5];
    const float* b2 = (const float*)d_in[6];
    const float* d2 = (const float*)d_in[7];
    const float* w3 = (const float*)d_in[8];
    const float* b3 = (const float*)d_in[9];
    const float* d3 = (const float*)d_in[10];
    const float* w4 = (const float*)d_in[11];
    const float* b4 = (const float*)d_in[12];
    const float* d4 = (const float*)d_in[13];
    const float* fcw = (const float*)d_in[14];
    const float* fcb = (const float*)d_in[15];

    const int B = 2, V1 = 8192, V2 = 2048, V3 = 512, NN = 50;

    // Workspace arenas (lifetimes disjoint within each arena). Peak 23.3 MB.
    char* ws = (char*)d_ws;
    float* arena1 = (float*)(ws + 0);          //  8,388,608 : fout1 / fout3 / fout4
    float* arena2 = (float*)(ws + 8388608);    //  4,194,304 : fm1 / fm3 / fm4
    float* arena3 = (float*)(ws + 12582912);   //  4,194,304 : fout2
    int*   arena4 = (int*)  (ws + 16777216);   //  3,276,800 : idxA / idxB / idxC
    float* arena5 = (float*)(ws + 20054016);   //  2,097,152 : fm0 / fm2
    float* arena6 = (float*)(ws + 22151168);   //  1,048,576 : fm1p / fm3p
    char*  arena7 = (ws + 23199744);           //     65,536 : idxP1 / idxP2 / feat

    // ---- Stage 1 (V=8192) ----
    int* idxA = arena4;
    knn_kernel<32, 51><<<B * V1, 256, 0, stream>>>(verts, V1, V1, idxA);

    float* fm0 = arena5;   // conv_surface -> relu
    conv_kernel<64><<<B * V1, 64, 0, stream>>>(idxA, verts, V1, V1, NN,
                                               nullptr, 32, dir0, fm0, 1);
    float* fout1 = arena1;
    gemm_bias<<<B * V1, 256, 0, stream>>>(fm0, w1, b1, fout1, 32, 128);
    float* fm1 = arena2;
    conv_kernel<64><<<B * V1, 64, 0, stream>>>(idxA, verts, V1, V1, NN,
                                               fout1, 64, d1, fm1, 1);
    // pool 8192 -> 2048 (4-NN over all 8192, rows 0..2047)
    int* idxP1 = (int*)arena7;
    knn_kernel<32, 5><<<B * V2, 256, 0, stream>>>(verts, V1, V2, idxP1);
    float* fm1p = arena6;
    pool_max<<<B * V2, 256, 0, stream>>>(idxP1, fm1, V1, V2, 64, fm1p);

    // ---- Stage 2 (V=2048) ----
    int* idxB = arena4;
    knn_kernel<8, 51><<<B * V2, 256, 0, stream>>>(verts, V1, V2, idxB);
    float* fout2 = arena3;
    gemm_bias<<<B * V2, 256, 0, stream>>>(fm1p, w2, b2, fout2, 64, 256);
    float* fm2 = arena5;
    conv_kernel<128><<<B * V2, 128, 0, stream>>>(idxB, verts, V1, V2, NN,
                                                 fout2, 128, d2, fm2, 1);
    float* fout3 = arena1;
    gemm_bias<<<B * V2, 256, 0, stream>>>(fm2, w3, b3, fout3, 128, 512);
    float* fm3 = arena2;
    conv_kernel<256><<<B * V2, 256, 0, stream>>>(idxB, verts, V1, V2, NN,
                                                 fout3, 256, d3, fm3, 1);
    // pool 2048 -> 512
    int* idxP2 = (int*)arena7;
    knn_kernel<8, 5><<<B * V3, 256, 0, stream>>>(verts, V1, V3, idxP2);
    float* fm3p = arena6;
    pool_max<<<B * V3, 256, 0, stream>>>(idxP2, fm3, V2, V3, 256, fm3p);

    // ---- Stage 3 (V=512) ----
    int* idxC = arena4;
    knn_kernel<2, 51><<<B * V3, 256, 0, stream>>>(verts, V1, V3, idxC);
    float* fout4 = arena1;
    gemm_bias<<<B * V3, 256, 0, stream>>>(fm3p, w4, b4, fout4, 256, 2048);
    float* fm4 = arena2;
    conv_kernel<256><<<B * V3, 256, 0, stream>>>(idxC, verts, V1, V3, NN,
                                                 fout4, 1024, d4, fm4, 0); // no relu
    // ---- Head ----
    float* feat = (float*)arena7;
    colmax<<<dim3(4, B), 256, 0, stream>>>(fm4, V3, 1024, feat);
    fc_kernel<<<B, 256, 0, stream>>>(feat, fcw, fcb, (float*)d_out);
}

// Round 2
// 1652.075 us; speedup vs baseline: 1.2025x; 1.2025x over previous
//
#include <hip/hip_runtime.h>
#include <cmath>

// ---------------------------------------------------------------------------
// PointCloudFeatureExtractor — full pipeline port (fp32).
// Round 2: barrier-free wave-local kNN selection + rank merge; tiled GEMM.
// ---------------------------------------------------------------------------

__device__ __forceinline__ unsigned long long shfl_xor_u64(unsigned long long x, int mask) {
    unsigned int lo = (unsigned int)(x & 0xffffffffull);
    unsigned int hi = (unsigned int)(x >> 32);
    lo = __shfl_xor(lo, mask, 64);
    hi = __shfl_xor(hi, mask, 64);
    return (((unsigned long long)hi) << 32) | lo;
}

__device__ __forceinline__ unsigned long long u64min(unsigned long long a, unsigned long long b) {
    return (a < b) ? a : b;
}

// kNN v2: one block (256 thr = 4 waves) per query row.
// Each wave independently selects its sorted top-SEL of its 64*CPT candidates
// (wave-synchronous, no barriers), then a rank-merge over the 4*SEL union
// produces the exact global top-SEL. Output: indices of ranks 1..SEL-1
// (drops rank 0 = self). Keys are (sortable_dist_bits<<32)|idx, unique, so
// ordering == jax.lax.top_k(-dist) with lower-index tie-break.
template <int CPT, int SEL>
__global__ __launch_bounds__(256) void knn_wave(
    const float* __restrict__ v,   // (B, vStride, 3)
    int vStride,
    int nRows,                     // query rows per batch
    int* __restrict__ outIdx)      // (B, nRows, SEL-1)
{
#pragma clang fp contract(off)
    const int tid  = threadIdx.x;
    const int lane = tid & 63;
    const int wid  = tid >> 6;
    const int bi   = blockIdx.x;          // b*nRows + row
    const int b    = bi / nRows;
    const int row  = bi % nRows;

    const float px = v[((size_t)b * vStride + row) * 3 + 0];
    const float py = v[((size_t)b * vStride + row) * 3 + 1];
    const float pz = v[((size_t)b * vStride + row) * 3 + 2];
    const float qrow = (px * px + py * py) + pz * pz;

    unsigned long long pk[CPT];
#pragma unroll
    for (int s = 0; s < CPT; ++s) {
        const int j = tid + (s << 8);
        const float cx = v[((size_t)b * vStride + j) * 3 + 0];
        const float cy = v[((size_t)b * vStride + j) * 3 + 1];
        const float cz = v[((size_t)b * vStride + j) * 3 + 2];
        const float inner = (px * cx + py * cy) + pz * cz;
        const float qc    = (cx * cx + cy * cy) + cz * cz;
        const float dist  = ((-2.0f * inner) + qc) + qrow;
        unsigned int u = __float_as_uint(dist);
        u = (u & 0x80000000u) ? ~u : (u | 0x80000000u);
        pk[s] = (((unsigned long long)u) << 32) | (unsigned int)j;
    }

    // group-min structure: groups of 8 slots
    constexpr int NG = (CPT + 7) / 8;
    unsigned long long gm[NG];
#pragma unroll
    for (int g = 0; g < NG; ++g) {
        unsigned long long m = ~0ull;
#pragma unroll
        for (int s = g * 8; s < ((g + 1) * 8 < CPT ? (g + 1) * 8 : CPT); ++s)
            m = u64min(m, pk[s]);
        gm[g] = m;
    }
    unsigned long long tm = ~0ull;
#pragma unroll
    for (int g = 0; g < NG; ++g) tm = u64min(tm, gm[g]);

    // wave-local selection loop (no barriers). Winners ascend, so removed
    // keys are always < current winner: rebuild group-min by filtering > m.
    unsigned long long mine = ~0ull;
    for (int it = 0; it < SEL; ++it) {
        unsigned long long m = tm;
#pragma unroll
        for (int off = 32; off > 0; off >>= 1)
            m = u64min(m, shfl_xor_u64(m, off));
        if (lane == it) mine = m;
        const int widx = (int)(m & 0xffffffffull);
        if ((widx & 63) == lane) {
            const int slot = widx >> 8;
            const int g = slot >> 3;
#pragma unroll
            for (int gg = 0; gg < NG; ++gg) {
                if (gg == g) {
                    unsigned long long mm = ~0ull;
#pragma unroll
                    for (int s = gg * 8; s < ((gg + 1) * 8 < CPT ? (gg + 1) * 8 : CPT); ++s) {
                        const unsigned long long cand = (pk[s] > m) ? pk[s] : ~0ull;
                        mm = u64min(mm, cand);
                    }
                    gm[gg] = mm;
                }
            }
            unsigned long long t2 = ~0ull;
#pragma unroll
            for (int g2 = 0; g2 < NG; ++g2) t2 = u64min(t2, gm[g2]);
            tm = t2;
        }
    }

    // merge 4 sorted wave-lists by rank count
    __shared__ unsigned long long sk[4 * SEL];
    if (lane < SEL) sk[wid * SEL + lane] = mine;
    __syncthreads();
    if (tid < 4 * SEL) {
        const unsigned long long k = sk[tid];
        int rank = 0;
        for (int i = 0; i < 4 * SEL; ++i) rank += (sk[i] < k) ? 1 : 0;
        if (rank >= 1 && rank < SEL)
            outIdx[(size_t)bi * (SEL - 1) + (rank - 1)] = (int)(k & 0xffffffffull);
    }
}

// Unified conv: if fout==nullptr this is conv_surface (f_support=1, f_center=0).
template <int NT>
__global__ __launch_bounds__(NT) void conv_kernel(
    const int*   __restrict__ idx,   // (B, V, NN)
    const float* __restrict__ v,     // (B, vStride, 3)
    int vStride, int V, int NN,
    const float* __restrict__ fout,  // (B, V, 2*oc) or nullptr
    int oc,
    const float* __restrict__ dirs,  // (3, oc)
    float* __restrict__ out,         // (B, V, oc)
    int do_relu)
{
#pragma clang fp contract(off)
    __shared__ float dnx[64], dny[64], dnz[64];
    __shared__ int   nb[64];
    const int bi  = blockIdx.x;     // b*V + i
    const int b   = bi / V;
    const int i   = bi % V;
    const int tid = threadIdx.x;

    if (tid < NN) {
        const int j = idx[(size_t)bi * NN + tid];
        nb[tid] = j;
        const float px = v[((size_t)b * vStride + i) * 3 + 0];
        const float py = v[((size_t)b * vStride + i) * 3 + 1];
        const float pz = v[((size_t)b * vStride + i) * 3 + 2];
        const float dx = v[((size_t)b * vStride + j) * 3 + 0] - px;
        const float dy = v[((size_t)b * vStride + j) * 3 + 1] - py;
        const float dz = v[((size_t)b * vStride + j) * 3 + 2] - pz;
        const float n  = sqrtf((dx * dx + dy * dy) + dz * dz);
        const float dn = fmaxf(n, 1e-12f);
        dnx[tid] = dx / dn;
        dny[tid] = dy / dn;
        dnz[tid] = dz / dn;
    }
    __syncthreads();

    for (int c = tid; c < oc; c += NT) {
        float d0 = dirs[c], d1 = dirs[oc + c], d2 = dirs[2 * oc + c];
        const float nd = sqrtf((d0 * d0 + d1 * d1) + d2 * d2);
        const float dc = fmaxf(nd, 1e-12f);
        d0 /= dc; d1 /= dc; d2 /= dc;

        float fcen = 0.f;
        if (fout) fcen = fout[(size_t)bi * (2 * oc) + c];

        float m = -INFINITY;
        for (int n = 0; n < NN; ++n) {
            float th = (dnx[n] * d0 + dny[n] * d1) + dnz[n] * d2;
            th = fmaxf(th, 0.f);
            float fs = 1.f;
            if (fout) fs = fout[((size_t)b * V + nb[n]) * (2 * oc) + oc + c];
            m = fmaxf(m, th * fs);
        }
        float r = fcen + m;
        if (do_relu) r = fmaxf(r, 0.f);
        out[(size_t)bi * oc + c] = r;
    }
}

// out(row, C) = A(row, ic) @ W(ic, C) + bias(C). R rows per block, register
// accumulators reuse each W element R times.
template <int R>
__global__ __launch_bounds__(256) void gemm_bias(
    const float* __restrict__ A, const float* __restrict__ W,
    const float* __restrict__ bias, float* __restrict__ out,
    int ic, int C)
{
    __shared__ float arow[R][256];
    const int r0  = blockIdx.x * R;
    const int tid = threadIdx.x;
#pragma unroll
    for (int r = 0; r < R; ++r)
        for (int k = tid; k < ic; k += 256)
            arow[r][k] = A[(size_t)(r0 + r) * ic + k];
    __syncthreads();
    for (int c = tid; c < C; c += 256) {
        float acc[R];
#pragma unroll
        for (int r = 0; r < R; ++r) acc[r] = bias[c];
        for (int k = 0; k < ic; ++k) {
            const float w = W[(size_t)k * C + c];
#pragma unroll
            for (int r = 0; r < R; ++r) acc[r] += arow[r][k] * w;
        }
#pragma unroll
        for (int r = 0; r < R; ++r) out[(size_t)(r0 + r) * C + c] = acc[r];
    }
}

// pooled[b,i,c] = max over 4 neighbors of fm[b, idx4[b,i,n], c]
__global__ __launch_bounds__(256) void pool_max(
    const int* __restrict__ idx4, const float* __restrict__ fm,
    int Vin, int pn, int C, float* __restrict__ out)
{
    const int bi  = blockIdx.x;      // b*pn + i
    const int b   = bi / pn;
    const int tid = threadIdx.x;
    const int j0 = idx4[(size_t)bi * 4 + 0];
    const int j1 = idx4[(size_t)bi * 4 + 1];
    const int j2 = idx4[(size_t)bi * 4 + 2];
    const int j3 = idx4[(size_t)bi * 4 + 3];
    for (int c = tid; c < C; c += 256) {
        float m = fm[((size_t)b * Vin + j0) * C + c];
        m = fmaxf(m, fm[((size_t)b * Vin + j1) * C + c]);
        m = fmaxf(m, fm[((size_t)b * Vin + j2) * C + c]);
        m = fmaxf(m, fm[((size_t)b * Vin + j3) * C + c]);
        out[(size_t)bi * C + c] = m;
    }
}

// feat[b,c] = max over V rows of fm[b,:,c]
__global__ __launch_bounds__(256) void colmax(
    const float* __restrict__ fm, int V, int C, float* __restrict__ out)
{
    const int b = blockIdx.y;
    const int c = blockIdx.x * 256 + threadIdx.x;
    if (c >= C) return;
    float m = -INFINITY;
    for (int i = 0; i < V; ++i) m = fmaxf(m, fm[((size_t)b * V + i) * C + c]);
    out[(size_t)b * C + c] = m;
}

// out[b, :256] = feat[b, :1024] @ W(1024,256) + bias
__global__ __launch_bounds__(256) void fc_kernel(
    const float* __restrict__ feat, const float* __restrict__ W,
    const float* __restrict__ bias, float* __restrict__ out)
{
    __shared__ float f[1024];
    const int b = blockIdx.x, tid = threadIdx.x;
    for (int k = tid; k < 1024; k += 256) f[k] = feat[(size_t)b * 1024 + k];
    __syncthreads();
    float acc = bias[tid];
    for (int k = 0; k < 1024; ++k) acc += f[k] * W[(size_t)k * 256 + tid];
    out[(size_t)b * 256 + tid] = acc;
}

extern "C" void kernel_launch(void* const* d_in, const int* in_sizes, int n_in,
                              void* d_out, int out_size, void* d_ws, size_t ws_size,
                              hipStream_t stream) {
    const float* verts = (const float*)d_in[0];
    const float* dir0  = (const float*)d_in[1];
    const float* w1 = (const float*)d_in[2];
    const float* b1 = (const float*)d_in[3];
    const float* d1 = (const float*)d_in[4];
    const float* w2 = (const float*)d_in[5];
    const float* b2 = (const float*)d_in[6];
    const float* d2 = (const float*)d_in[7];
    const float* w3 = (const float*)d_in[8];
    const float* b3 = (const float*)d_in[9];
    const float* d3 = (const float*)d_in[10];
    const float* w4 = (const float*)d_in[11];
    const float* b4 = (const float*)d_in[12];
    const float* d4 = (const float*)d_in[13];
    const float* fcw = (const float*)d_in[14];
    const float* fcb = (const float*)d_in[15];

    const int B = 2, V1 = 8192, V2 = 2048, V3 = 512, NN = 50;

    char* ws = (char*)d_ws;
    float* arena1 = (float*)(ws + 0);          //  8,388,608 : fout1 / fout3 / fout4
    float* arena2 = (float*)(ws + 8388608);    //  4,194,304 : fm1 / fm3 / fm4
    float* arena3 = (float*)(ws + 12582912);   //  4,194,304 : fout2
    int*   arena4 = (int*)  (ws + 16777216);   //  3,276,800 : idxA / idxB / idxC
    float* arena5 = (float*)(ws + 20054016);   //  2,097,152 : fm0 / fm2
    float* arena6 = (float*)(ws + 22151168);   //  1,048,576 : fm1p / fm3p
    char*  arena7 = (ws + 23199744);           //     65,536 : idxP1 / idxP2 / feat

    // ---- Stage 1 (V=8192) ----
    int* idxA = arena4;
    knn_wave<32, 51><<<B * V1, 256, 0, stream>>>(verts, V1, V1, idxA);

    float* fm0 = arena5;
    conv_kernel<64><<<B * V1, 64, 0, stream>>>(idxA, verts, V1, V1, NN,
                                               nullptr, 32, dir0, fm0, 1);
    float* fout1 = arena1;
    gemm_bias<8><<<B * V1 / 8, 256, 0, stream>>>(fm0, w1, b1, fout1, 32, 128);
    float* fm1 = arena2;
    conv_kernel<64><<<B * V1, 64, 0, stream>>>(idxA, verts, V1, V1, NN,
                                               fout1, 64, d1, fm1, 1);
    // pool 8192 -> 2048
    int* idxP1 = (int*)arena7;
    knn_wave<32, 5><<<B * V2, 256, 0, stream>>>(verts, V1, V2, idxP1);
    float* fm1p = arena6;
    pool_max<<<B * V2, 256, 0, stream>>>(idxP1, fm1, V1, V2, 64, fm1p);

    // ---- Stage 2 (V=2048) ----
    int* idxB = arena4;
    knn_wave<8, 51><<<B * V2, 256, 0, stream>>>(verts, V1, V2, idxB);
    float* fout2 = arena3;
    gemm_bias<8><<<B * V2 / 8, 256, 0, stream>>>(fm1p, w2, b2, fout2, 64, 256);
    float* fm2 = arena5;
    conv_kernel<128><<<B * V2, 128, 0, stream>>>(idxB, verts, V1, V2, NN,
                                                 fout2, 128, d2, fm2, 1);
    float* fout3 = arena1;
    gemm_bias<8><<<B * V2 / 8, 256, 0, stream>>>(fm2, w3, b3, fout3, 128, 512);
    float* fm3 = arena2;
    conv_kernel<256><<<B * V2, 256, 0, stream>>>(idxB, verts, V1, V2, NN,
                                                 fout3, 256, d3, fm3, 1);
    // pool 2048 -> 512
    int* idxP2 = (int*)arena7;
    knn_wave<8, 5><<<B * V3, 256, 0, stream>>>(verts, V1, V3, idxP2);
    float* fm3p = arena6;
    pool_max<<<B * V3, 256, 0, stream>>>(idxP2, fm3, V2, V3, 256, fm3p);

    // ---- Stage 3 (V=512) ----
    int* idxC = arena4;
    knn_wave<2, 51><<<B * V3, 256, 0, stream>>>(verts, V1, V3, idxC);
    float* fout4 = arena1;
    gemm_bias<4><<<B * V3 / 4, 256, 0, stream>>>(fm3p, w4, b4, fout4, 256, 2048);
    float* fm4 = arena2;
    conv_kernel<256><<<B * V3, 256, 0, stream>>>(idxC, verts, V1, V3, NN,
                                                 fout4, 1024, d4, fm4, 0);
    // ---- Head ----
    float* feat = (float*)arena7;
    colmax<<<dim3(4, B), 256, 0, stream>>>(fm4, V3, 1024, feat);
    fc_kernel<<<B, 256, 0, stream>>>(feat, fcw, fcb, (float*)d_out);
}

// Round 3
// 808.842 us; speedup vs baseline: 2.4562x; 2.0425x over previous
//
#include <hip/hip_runtime.h>
#include <cmath>

// ---------------------------------------------------------------------------
// PointCloudFeatureExtractor — full pipeline port (fp32).
// Round 3: threshold-based exact kNN selection (no serial argmin loop).
// ---------------------------------------------------------------------------

// kNN v3: one block (256 threads) per query row; candidates = 256*CPT rows.
// Exact top-SEL (incl. self) via:
//   1) per-thread local min (u64 key = sortable_dist<<32 | idx)
//   2) T = (SEL)th smallest of the 256 local minima  (upper bound on the
//      true SEL-th smallest key: the SEL minima <= T are actual keys)
//   3) extract all keys <= T (provably <= SEL*CPT survivors)
//   4) exact rank-count over survivors; ranks 1..SEL-1 -> output.
// Key uniqueness (idx in low bits) makes ordering identical to
// jax.lax.top_k(-dist) with lower-index tie-break.
template <int CPT, int SEL>
__global__ __launch_bounds__(256) void knn_select(
    const float* __restrict__ v,   // (B, vStride, 3)
    int vStride,
    int nRows,                     // query rows per batch
    int* __restrict__ outIdx)      // (B, nRows, SEL-1)
{
#pragma clang fp contract(off)
    const int tid = threadIdx.x;
    const int bi  = blockIdx.x;          // b*nRows + row
    const int b   = bi / nRows;
    const int row = bi % nRows;
    const float* vb = v + (size_t)b * vStride * 3;

    const float px = vb[row * 3 + 0];
    const float py = vb[row * 3 + 1];
    const float pz = vb[row * 3 + 2];
    const float qrow = (px * px + py * py) + pz * pz;

    unsigned int ku[CPT];
    unsigned long long lmin = ~0ull;
#pragma unroll
    for (int s = 0; s < CPT; ++s) {
        const int j = tid + (s << 8);
        const float cx = vb[j * 3 + 0];
        const float cy = vb[j * 3 + 1];
        const float cz = vb[j * 3 + 2];
        const float inner = (px * cx + py * cy) + pz * cz;
        const float qc    = (cx * cx + cy * cy) + cz * cz;
        const float dist  = ((-2.0f * inner) + qc) + qrow;
        unsigned int u = __float_as_uint(dist);
        u = (u & 0x80000000u) ? ~u : (u | 0x80000000u);
        ku[s] = u;
        const unsigned long long k64 =
            (((unsigned long long)u) << 32) | (unsigned int)j;
        if (k64 < lmin) lmin = k64;
    }

    constexpr int CAP = (CPT * SEL > 256) ? CPT * SEL : 256;
    __shared__ unsigned long long buf[CAP];
    __shared__ unsigned long long T_s;
    __shared__ int cnt;

    buf[tid] = lmin;
    __syncthreads();

    // rank own local-min among the 256 minima (broadcast LDS scan)
    int rank = 0;
#pragma unroll 4
    for (int i = 0; i < 256; ++i) rank += (buf[i] < lmin) ? 1 : 0;
    if (rank == SEL - 1) T_s = lmin;     // exactly one thread (keys unique)
    if (tid == 0) cnt = 0;
    __syncthreads();

    const unsigned long long T = T_s;

    // extract survivors (keys <= T); M <= SEL*CPT by construction
#pragma unroll
    for (int s = 0; s < CPT; ++s) {
        const unsigned long long k64 =
            (((unsigned long long)ku[s]) << 32) | (unsigned int)(tid + (s << 8));
        if (k64 <= T) {
            const int p = atomicAdd(&cnt, 1);
            buf[p] = k64;
        }
    }
    __syncthreads();

    const int M = cnt;
    for (int s2 = tid; s2 < M; s2 += 256) {
        const unsigned long long k = buf[s2];
        int r = 0;
        for (int i = 0; i < M; ++i) r += (buf[i] < k) ? 1 : 0;
        if (r >= 1 && r < SEL)
            outIdx[(size_t)bi * (SEL - 1) + (r - 1)] = (int)(k & 0xffffffffu);
    }
}

// Unified conv: if fout==nullptr this is conv_surface (f_support=1, f_center=0).
template <int NT>
__global__ __launch_bounds__(NT) void conv_kernel(
    const int*   __restrict__ idx,   // (B, V, NN)
    const float* __restrict__ v,     // (B, vStride, 3)
    int vStride, int V, int NN,
    const float* __restrict__ fout,  // (B, V, 2*oc) or nullptr
    int oc,
    const float* __restrict__ dirs,  // (3, oc)
    float* __restrict__ out,         // (B, V, oc)
    int do_relu)
{
#pragma clang fp contract(off)
    __shared__ float dnx[64], dny[64], dnz[64];
    __shared__ int   nb[64];
    const int bi  = blockIdx.x;     // b*V + i
    const int b   = bi / V;
    const int i   = bi % V;
    const int tid = threadIdx.x;

    if (tid < NN) {
        const int j = idx[(size_t)bi * NN + tid];
        nb[tid] = j;
        const float px = v[((size_t)b * vStride + i) * 3 + 0];
        const float py = v[((size_t)b * vStride + i) * 3 + 1];
        const float pz = v[((size_t)b * vStride + i) * 3 + 2];
        const float dx = v[((size_t)b * vStride + j) * 3 + 0] - px;
        const float dy = v[((size_t)b * vStride + j) * 3 + 1] - py;
        const float dz = v[((size_t)b * vStride + j) * 3 + 2] - pz;
        const float n  = sqrtf((dx * dx + dy * dy) + dz * dz);
        const float dn = fmaxf(n, 1e-12f);
        dnx[tid] = dx / dn;
        dny[tid] = dy / dn;
        dnz[tid] = dz / dn;
    }
    __syncthreads();

    for (int c = tid; c < oc; c += NT) {
        float d0 = dirs[c], d1 = dirs[oc + c], d2 = dirs[2 * oc + c];
        const float nd = sqrtf((d0 * d0 + d1 * d1) + d2 * d2);
        const float dc = fmaxf(nd, 1e-12f);
        d0 /= dc; d1 /= dc; d2 /= dc;

        float fcen = 0.f;
        if (fout) fcen = fout[(size_t)bi * (2 * oc) + c];

        float m = -INFINITY;
        for (int n = 0; n < NN; ++n) {
            float th = (dnx[n] * d0 + dny[n] * d1) + dnz[n] * d2;
            th = fmaxf(th, 0.f);
            float fs = 1.f;
            if (fout) fs = fout[((size_t)b * V + nb[n]) * (2 * oc) + oc + c];
            m = fmaxf(m, th * fs);
        }
        float r = fcen + m;
        if (do_relu) r = fmaxf(r, 0.f);
        out[(size_t)bi * oc + c] = r;
    }
}

// out(row, C) = A(row, ic) @ W(ic, C) + bias(C). R rows per block.
template <int R>
__global__ __launch_bounds__(256) void gemm_bias(
    const float* __restrict__ A, const float* __restrict__ W,
    const float* __restrict__ bias, float* __restrict__ out,
    int ic, int C)
{
    __shared__ float arow[R][256];
    const int r0  = blockIdx.x * R;
    const int tid = threadIdx.x;
#pragma unroll
    for (int r = 0; r < R; ++r)
        for (int k = tid; k < ic; k += 256)
            arow[r][k] = A[(size_t)(r0 + r) * ic + k];
    __syncthreads();
    for (int c = tid; c < C; c += 256) {
        float acc[R];
#pragma unroll
        for (int r = 0; r < R; ++r) acc[r] = bias[c];
        for (int k = 0; k < ic; ++k) {
            const float w = W[(size_t)k * C + c];
#pragma unroll
            for (int r = 0; r < R; ++r) acc[r] += arow[r][k] * w;
        }
#pragma unroll
        for (int r = 0; r < R; ++r) out[(size_t)(r0 + r) * C + c] = acc[r];
    }
}

// pooled[b,i,c] = max over 4 neighbors of fm[b, idx4[b,i,n], c]
__global__ __launch_bounds__(256) void pool_max(
    const int* __restrict__ idx4, const float* __restrict__ fm,
    int Vin, int pn, int C, float* __restrict__ out)
{
    const int bi  = blockIdx.x;      // b*pn + i
    const int b   = bi / pn;
    const int tid = threadIdx.x;
    const int j0 = idx4[(size_t)bi * 4 + 0];
    const int j1 = idx4[(size_t)bi * 4 + 1];
    const int j2 = idx4[(size_t)bi * 4 + 2];
    const int j3 = idx4[(size_t)bi * 4 + 3];
    for (int c = tid; c < C; c += 256) {
        float m = fm[((size_t)b * Vin + j0) * C + c];
        m = fmaxf(m, fm[((size_t)b * Vin + j1) * C + c]);
        m = fmaxf(m, fm[((size_t)b * Vin + j2) * C + c]);
        m = fmaxf(m, fm[((size_t)b * Vin + j3) * C + c]);
        out[(size_t)bi * C + c] = m;
    }
}

// feat[b,c] = max over V rows of fm[b,:,c]
__global__ __launch_bounds__(256) void colmax(
    const float* __restrict__ fm, int V, int C, float* __restrict__ out)
{
    const int b = blockIdx.y;
    const int c = blockIdx.x * 256 + threadIdx.x;
    if (c >= C) return;
    float m = -INFINITY;
    for (int i = 0; i < V; ++i) m = fmaxf(m, fm[((size_t)b * V + i) * C + c]);
    out[(size_t)b * C + c] = m;
}

// out[b, :256] = feat[b, :1024] @ W(1024,256) + bias
__global__ __launch_bounds__(256) void fc_kernel(
    const float* __restrict__ feat, const float* __restrict__ W,
    const float* __restrict__ bias, float* __restrict__ out)
{
    __shared__ float f[1024];
    const int b = blockIdx.x, tid = threadIdx.x;
    for (int k = tid; k < 1024; k += 256) f[k] = feat[(size_t)b * 1024 + k];
    __syncthreads();
    float acc = bias[tid];
    for (int k = 0; k < 1024; ++k) acc += f[k] * W[(size_t)k * 256 + tid];
    out[(size_t)b * 256 + tid] = acc;
}

extern "C" void kernel_launch(void* const* d_in, const int* in_sizes, int n_in,
                              void* d_out, int out_size, void* d_ws, size_t ws_size,
                              hipStream_t stream) {
    const float* verts = (const float*)d_in[0];
    const float* dir0  = (const float*)d_in[1];
    const float* w1 = (const float*)d_in[2];
    const float* b1 = (const float*)d_in[3];
    const float* d1 = (const float*)d_in[4];
    const float* w2 = (const float*)d_in[5];
    const float* b2 = (const float*)d_in[6];
    const float* d2 = (const float*)d_in[7];
    const float* w3 = (const float*)d_in[8];
    const float* b3 = (const float*)d_in[9];
    const float* d3 = (const float*)d_in[10];
    const float* w4 = (const float*)d_in[11];
    const float* b4 = (const float*)d_in[12];
    const float* d4 = (const float*)d_in[13];
    const float* fcw = (const float*)d_in[14];
    const float* fcb = (const float*)d_in[15];

    const int B = 2, V1 = 8192, V2 = 2048, V3 = 512, NN = 50;

    char* ws = (char*)d_ws;
    float* arena1 = (float*)(ws + 0);          //  8,388,608 : fout1 / fout3 / fout4
    float* arena2 = (float*)(ws + 8388608);    //  4,194,304 : fm1 / fm3 / fm4
    float* arena3 = (float*)(ws + 12582912);   //  4,194,304 : fout2
    int*   arena4 = (int*)  (ws + 16777216);   //  3,276,800 : idxA / idxB / idxC
    float* arena5 = (float*)(ws + 20054016);   //  2,097,152 : fm0 / fm2
    float* arena6 = (float*)(ws + 22151168);   //  1,048,576 : fm1p / fm3p
    char*  arena7 = (ws + 23199744);           //     65,536 : idxP1 / idxP2 / feat

    // ---- Stage 1 (V=8192) ----
    int* idxA = arena4;
    knn_select<32, 51><<<B * V1, 256, 0, stream>>>(verts, V1, V1, idxA);

    float* fm0 = arena5;
    conv_kernel<64><<<B * V1, 64, 0, stream>>>(idxA, verts, V1, V1, NN,
                                               nullptr, 32, dir0, fm0, 1);
    float* fout1 = arena1;
    gemm_bias<8><<<B * V1 / 8, 256, 0, stream>>>(fm0, w1, b1, fout1, 32, 128);
    float* fm1 = arena2;
    conv_kernel<64><<<B * V1, 64, 0, stream>>>(idxA, verts, V1, V1, NN,
                                               fout1, 64, d1, fm1, 1);
    // pool 8192 -> 2048
    int* idxP1 = (int*)arena7;
    knn_select<32, 5><<<B * V2, 256, 0, stream>>>(verts, V1, V2, idxP1);
    float* fm1p = arena6;
    pool_max<<<B * V2, 256, 0, stream>>>(idxP1, fm1, V1, V2, 64, fm1p);

    // ---- Stage 2 (V=2048) ----
    int* idxB = arena4;
    knn_select<8, 51><<<B * V2, 256, 0, stream>>>(verts, V1, V2, idxB);
    float* fout2 = arena3;
    gemm_bias<8><<<B * V2 / 8, 256, 0, stream>>>(fm1p, w2, b2, fout2, 64, 256);
    float* fm2 = arena5;
    conv_kernel<128><<<B * V2, 128, 0, stream>>>(idxB, verts, V1, V2, NN,
                                                 fout2, 128, d2, fm2, 1);
    float* fout3 = arena1;
    gemm_bias<8><<<B * V2 / 8, 256, 0, stream>>>(fm2, w3, b3, fout3, 128, 512);
    float* fm3 = arena2;
    conv_kernel<256><<<B * V2, 256, 0, stream>>>(idxB, verts, V1, V2, NN,
                                                 fout3, 256, d3, fm3, 1);
    // pool 2048 -> 512
    int* idxP2 = (int*)arena7;
    knn_select<8, 5><<<B * V3, 256, 0, stream>>>(verts, V1, V3, idxP2);
    float* fm3p = arena6;
    pool_max<<<B * V3, 256, 0, stream>>>(idxP2, fm3, V2, V3, 256, fm3p);

    // ---- Stage 3 (V=512) ----
    int* idxC = arena4;
    knn_select<2, 51><<<B * V3, 256, 0, stream>>>(verts, V1, V3, idxC);
    float* fout4 = arena1;
    gemm_bias<4><<<B * V3 / 4, 256, 0, stream>>>(fm3p, w4, b4, fout4, 256, 2048);
    float* fm4 = arena2;
    conv_kernel<256><<<B * V3, 256, 0, stream>>>(idxC, verts, V1, V3, NN,
                                                 fout4, 1024, d4, fm4, 0);
    // ---- Head ----
    float* feat = (float*)arena7;
    colmax<<<dim3(4, B), 256, 0, stream>>>(fm4, V3, 1024, feat);
    fc_kernel<<<B, 256, 0, stream>>>(feat, fcw, fcb, (float*)d_out);
}

// Round 4
// 430.436 us; speedup vs baseline: 4.6155x; 1.8791x over previous
//
#include <hip/hip_runtime.h>
#include <cmath>

// ---------------------------------------------------------------------------
// PointCloudFeatureExtractor — full pipeline port (fp32).
// Round 4: tiled GEMM (latency fix), kNN with precomputed q + u32 min/scan,
//          split column-max.
// ---------------------------------------------------------------------------

// q[i] = |v_i|^2 with the exact op order used by the knn distance formula.
__global__ __launch_bounds__(256) void precompute_q(
    const float* __restrict__ v, float* __restrict__ q, int n)
{
#pragma clang fp contract(off)
    const int i = blockIdx.x * 256 + threadIdx.x;
    if (i < n) {
        const float x = v[i * 3 + 0];
        const float y = v[i * 3 + 1];
        const float z = v[i * 3 + 2];
        q[i] = (x * x + y * y) + z * z;
    }
}

// kNN v4: one block (256 threads) per query row; candidates = 256*CPT rows.
//  1) per-thread local min of flipped-u32 distance keys
//  2) T = max{h : strict-rank(h) < SEL} over the 256 local minima
//     (>= SEL actual keys are <= T; survivors <= SEL*CPT)
//  3) extract keys <= T, exact u64 rank-count -> ranks 1..SEL-1.
// Distance math is bit-identical to the validated round-1 kernel.
template <int CPT, int SEL>
__global__ __launch_bounds__(256) void knn_select(
    const float* __restrict__ v, const float* __restrict__ qarr,
    int vStride, int nRows, int* __restrict__ outIdx)
{
#pragma clang fp contract(off)
    const int tid = threadIdx.x;
    const int bi  = blockIdx.x;          // b*nRows + row
    const int b   = bi / nRows;
    const int row = bi % nRows;
    const float* vb = v + (size_t)b * vStride * 3;
    const float* qb = qarr + (size_t)b * vStride;

    const float px = vb[row * 3 + 0];
    const float py = vb[row * 3 + 1];
    const float pz = vb[row * 3 + 2];
    const float qrow = qb[row];

    unsigned ku[CPT];
    unsigned umin = 0xffffffffu;
    int jmin = 0;
#pragma unroll
    for (int s = 0; s < CPT; ++s) {
        const int j = tid + (s << 8);
        const float cx = vb[j * 3 + 0];
        const float cy = vb[j * 3 + 1];
        const float cz = vb[j * 3 + 2];
        const float inner = (px * cx + py * cy) + pz * cz;
        const float dist  = ((-2.0f * inner) + qb[j]) + qrow;
        unsigned u = __float_as_uint(dist);
        u = (u & 0x80000000u) ? ~u : (u | 0x80000000u);
        ku[s] = u;
        if (u < umin) { umin = u; jmin = j; }   // strict: keeps lower j on tie
    }
    (void)jmin;

    constexpr int CAP = (CPT * SEL > 256) ? CPT * SEL : 256;
    __shared__ unsigned long long buf[CAP];
    __shared__ unsigned T_s;
    __shared__ int cnt;
    unsigned* hbuf = (unsigned*)buf;     // aliases buf; dead before extraction

    hbuf[tid] = umin;
    if (tid == 0) { T_s = 0u; cnt = 0; }
    __syncthreads();

    int r = 0;
#pragma unroll 8
    for (int i = 0; i < 256; ++i) r += (hbuf[i] < umin) ? 1 : 0;
    if (r < SEL) atomicMax(&T_s, umin);
    __syncthreads();
    const unsigned T = T_s;

#pragma unroll
    for (int s = 0; s < CPT; ++s) {
        const unsigned u = ku[s];
        if (u <= T) {
            const int j = tid + (s << 8);
            const int p = atomicAdd(&cnt, 1);
            buf[p] = (((unsigned long long)u) << 32) | (unsigned)j;
        }
    }
    __syncthreads();

    const int M = cnt;
    for (int s2 = tid; s2 < M; s2 += 256) {
        const unsigned long long k = buf[s2];
        int rr = 0;
        for (int i = 0; i < M; ++i) rr += (buf[i] < k) ? 1 : 0;
        if (rr >= 1 && rr < SEL)
            outIdx[(size_t)bi * (SEL - 1) + (rr - 1)] = (int)(k & 0xffffffffu);
    }
}

// Unified conv: if fout==nullptr this is conv_surface (f_support=1, f_center=0).
template <int NT>
__global__ __launch_bounds__(NT) void conv_kernel(
    const int*   __restrict__ idx,   // (B, V, NN)
    const float* __restrict__ v,     // (B, vStride, 3)
    int vStride, int V, int NN,
    const float* __restrict__ fout,  // (B, V, 2*oc) or nullptr
    int oc,
    const float* __restrict__ dirs,  // (3, oc)
    float* __restrict__ out,         // (B, V, oc)
    int do_relu)
{
#pragma clang fp contract(off)
    __shared__ float dnx[64], dny[64], dnz[64];
    __shared__ int   nb[64];
    const int bi  = blockIdx.x;     // b*V + i
    const int b   = bi / V;
    const int i   = bi % V;
    const int tid = threadIdx.x;

    if (tid < NN) {
        const int j = idx[(size_t)bi * NN + tid];
        nb[tid] = j;
        const float px = v[((size_t)b * vStride + i) * 3 + 0];
        const float py = v[((size_t)b * vStride + i) * 3 + 1];
        const float pz = v[((size_t)b * vStride + i) * 3 + 2];
        const float dx = v[((size_t)b * vStride + j) * 3 + 0] - px;
        const float dy = v[((size_t)b * vStride + j) * 3 + 1] - py;
        const float dz = v[((size_t)b * vStride + j) * 3 + 2] - pz;
        const float n  = sqrtf((dx * dx + dy * dy) + dz * dz);
        const float dn = fmaxf(n, 1e-12f);
        dnx[tid] = dx / dn;
        dny[tid] = dy / dn;
        dnz[tid] = dz / dn;
    }
    __syncthreads();

    for (int c = tid; c < oc; c += NT) {
        float d0 = dirs[c], d1 = dirs[oc + c], d2 = dirs[2 * oc + c];
        const float nd = sqrtf((d0 * d0 + d1 * d1) + d2 * d2);
        const float dc = fmaxf(nd, 1e-12f);
        d0 /= dc; d1 /= dc; d2 /= dc;

        float fcen = 0.f;
        if (fout) fcen = fout[(size_t)bi * (2 * oc) + c];

        float m = -INFINITY;
        for (int n = 0; n < NN; ++n) {
            float th = (dnx[n] * d0 + dny[n] * d1) + dnz[n] * d2;
            th = fmaxf(th, 0.f);
            float fs = 1.f;
            if (fout) fs = fout[((size_t)b * V + nb[n]) * (2 * oc) + oc + c];
            m = fmaxf(m, th * fs);
        }
        float r = fcen + m;
        if (do_relu) r = fmaxf(r, 0.f);
        out[(size_t)bi * oc + c] = r;
    }
}

// out(M,N) = A(M,K) @ W(K,N) + bias(N). 64x64 tile, BK=32, 256 threads,
// 4x4 per thread. A staged transposed in LDS (pad 68 -> aligned, conflict-
// free b128 reads). Accumulation order identical to the round-3 kernel
// (acc = bias, then k ascending, fma).
__global__ __launch_bounds__(256) void gemm_tiled(
    const float* __restrict__ A, const float* __restrict__ W,
    const float* __restrict__ bias, float* __restrict__ out,
    int M, int K, int N)
{
    __shared__ float As[32][68];
    __shared__ float Bs[32][64];
    const int tid = threadIdx.x;
    const int tx = tid & 15, ty = tid >> 4;
    const int r0 = blockIdx.x * 64;
    const int c0 = blockIdx.y * 64;

    const float4 bv = *(const float4*)&bias[c0 + tx * 4];
    float acc[4][4];
#pragma unroll
    for (int i = 0; i < 4; ++i) {
        acc[i][0] = bv.x; acc[i][1] = bv.y; acc[i][2] = bv.z; acc[i][3] = bv.w;
    }

    const int rowA = tid >> 2;       // 0..63
    const int ca4  = tid & 3;        // float4-col: ca4 and ca4+4
    const int rowB = tid >> 4;       // 0..15 (and +16)
    const int cb4  = tid & 15;       // float4-col

    for (int k0 = 0; k0 < K; k0 += 32) {
        const float4 a0 = *(const float4*)&A[(size_t)(r0 + rowA) * K + k0 + ca4 * 4];
        const float4 a1 = *(const float4*)&A[(size_t)(r0 + rowA) * K + k0 + (ca4 + 4) * 4];
        const float4 b0 = *(const float4*)&W[(size_t)(k0 + rowB) * N + c0 + cb4 * 4];
        const float4 b1 = *(const float4*)&W[(size_t)(k0 + rowB + 16) * N + c0 + cb4 * 4];
        __syncthreads();               // previous tile fully consumed
        As[ca4 * 4 + 0][rowA] = a0.x;
        As[ca4 * 4 + 1][rowA] = a0.y;
        As[ca4 * 4 + 2][rowA] = a0.z;
        As[ca4 * 4 + 3][rowA] = a0.w;
        As[ca4 * 4 + 16][rowA] = a1.x;
        As[ca4 * 4 + 17][rowA] = a1.y;
        As[ca4 * 4 + 18][rowA] = a1.z;
        As[ca4 * 4 + 19][rowA] = a1.w;
        *(float4*)&Bs[rowB][cb4 * 4]      = b0;
        *(float4*)&Bs[rowB + 16][cb4 * 4] = b1;
        __syncthreads();
#pragma unroll
        for (int kk = 0; kk < 32; ++kk) {
            const float4 av = *(const float4*)&As[kk][ty * 4];
            const float4 wv = *(const float4*)&Bs[kk][tx * 4];
            acc[0][0] += av.x * wv.x; acc[0][1] += av.x * wv.y;
            acc[0][2] += av.x * wv.z; acc[0][3] += av.x * wv.w;
            acc[1][0] += av.y * wv.x; acc[1][1] += av.y * wv.y;
            acc[1][2] += av.y * wv.z; acc[1][3] += av.y * wv.w;
            acc[2][0] += av.z * wv.x; acc[2][1] += av.z * wv.y;
            acc[2][2] += av.z * wv.z; acc[2][3] += av.z * wv.w;
            acc[3][0] += av.w * wv.x; acc[3][1] += av.w * wv.y;
            acc[3][2] += av.w * wv.z; acc[3][3] += av.w * wv.w;
        }
    }
#pragma unroll
    for (int i = 0; i < 4; ++i) {
        float4 o;
        o.x = acc[i][0]; o.y = acc[i][1]; o.z = acc[i][2]; o.w = acc[i][3];
        *(float4*)&out[(size_t)(r0 + ty * 4 + i) * N + c0 + tx * 4] = o;
    }
}

// pooled[b,i,c] = max over 4 neighbors of fm[b, idx4[b,i,n], c]
__global__ __launch_bounds__(256) void pool_max(
    const int* __restrict__ idx4, const float* __restrict__ fm,
    int Vin, int pn, int C, float* __restrict__ out)
{
    const int bi  = blockIdx.x;      // b*pn + i
    const int b   = bi / pn;
    const int tid = threadIdx.x;
    const int j0 = idx4[(size_t)bi * 4 + 0];
    const int j1 = idx4[(size_t)bi * 4 + 1];
    const int j2 = idx4[(size_t)bi * 4 + 2];
    const int j3 = idx4[(size_t)bi * 4 + 3];
    for (int c = tid; c < C; c += 256) {
        float m = fm[((size_t)b * Vin + j0) * C + c];
        m = fmaxf(m, fm[((size_t)b * Vin + j1) * C + c]);
        m = fmaxf(m, fm[((size_t)b * Vin + j2) * C + c]);
        m = fmaxf(m, fm[((size_t)b * Vin + j3) * C + c]);
        out[(size_t)bi * C + c] = m;
    }
}

// partial column max over a chunk of rows. grid (C/256, B, nChunk).
__global__ __launch_bounds__(256) void colmax_part(
    const float* __restrict__ fm, int V, int C, int rowsPerChunk,
    float* __restrict__ part)
{
    const int b = blockIdx.y, chunk = blockIdx.z;
    const int nChunk = gridDim.z;
    const int c = blockIdx.x * 256 + threadIdx.x;
    const int i0 = chunk * rowsPerChunk;
    float m = -INFINITY;
    for (int i = i0; i < i0 + rowsPerChunk; ++i)
        m = fmaxf(m, fm[((size_t)b * V + i) * C + c]);
    part[((size_t)b * nChunk + chunk) * C + c] = m;
}

// out[b, :256] = (max-merge of partials)[b, :1024] @ W(1024,256) + bias
__global__ __launch_bounds__(256) void fc_kernel(
    const float* __restrict__ part, const float* __restrict__ W,
    const float* __restrict__ bias, float* __restrict__ out, int nChunk)
{
    __shared__ float f[1024];
    const int b = blockIdx.x, tid = threadIdx.x;
    for (int k = tid; k < 1024; k += 256) {
        float m = part[((size_t)b * nChunk) * 1024 + k];
        for (int ch = 1; ch < nChunk; ++ch)
            m = fmaxf(m, part[((size_t)b * nChunk + ch) * 1024 + k]);
        f[k] = m;
    }
    __syncthreads();
    float acc = bias[tid];
    for (int k = 0; k < 1024; ++k) acc += f[k] * W[(size_t)k * 256 + tid];
    out[(size_t)b * 256 + tid] = acc;
}

extern "C" void kernel_launch(void* const* d_in, const int* in_sizes, int n_in,
                              void* d_out, int out_size, void* d_ws, size_t ws_size,
                              hipStream_t stream) {
    const float* verts = (const float*)d_in[0];
    const float* dir0  = (const float*)d_in[1];
    const float* w1 = (const float*)d_in[2];
    const float* b1 = (const float*)d_in[3];
    const float* d1 = (const float*)d_in[4];
    const float* w2 = (const float*)d_in[5];
    const float* b2 = (const float*)d_in[6];
    const float* d2 = (const float*)d_in[7];
    const float* w3 = (const float*)d_in[8];
    const float* b3 = (const float*)d_in[9];
    const float* d3 = (const float*)d_in[10];
    const float* w4 = (const float*)d_in[11];
    const float* b4 = (const float*)d_in[12];
    const float* d4 = (const float*)d_in[13];
    const float* fcw = (const float*)d_in[14];
    const float* fcb = (const float*)d_in[15];

    const int B = 2, V1 = 8192, V2 = 2048, V3 = 512, NN = 50;

    char* ws = (char*)d_ws;
    float* arena1 = (float*)(ws + 0);          //  8,388,608 : fout1 / fout3 / fout4
    float* arena2 = (float*)(ws + 8388608);    //  4,194,304 : fm1 / fm3 / fm4
    float* arena3 = (float*)(ws + 12582912);   //  4,194,304 : fout2
    int*   arena4 = (int*)  (ws + 16777216);   //  3,276,800 : idxA / idxB / idxC
    float* arena5 = (float*)(ws + 20054016);   //  2,097,152 : fm0 / fm2
    float* arena6 = (float*)(ws + 22151168);   //  1,048,576 : fm1p / fm3p
    char*  arena7 = (ws + 23199744);           //     65,536 : idxP1 / idxP2
    float* part   = (float*)(ws + 23265280);   //     65,536 : colmax partials
    float* qarr   = (float*)(ws + 23330816);   //     65,536 : |v|^2 per point

    precompute_q<<<(B * V1 + 255) / 256, 256, 0, stream>>>(verts, qarr, B * V1);

    // ---- Stage 1 (V=8192) ----
    int* idxA = arena4;
    knn_select<32, 51><<<B * V1, 256, 0, stream>>>(verts, qarr, V1, V1, idxA);

    float* fm0 = arena5;
    conv_kernel<64><<<B * V1, 64, 0, stream>>>(idxA, verts, V1, V1, NN,
                                               nullptr, 32, dir0, fm0, 1);
    float* fout1 = arena1;
    gemm_tiled<<<dim3(B * V1 / 64, 128 / 64), 256, 0, stream>>>(
        fm0, w1, b1, fout1, B * V1, 32, 128);
    float* fm1 = arena2;
    conv_kernel<64><<<B * V1, 64, 0, stream>>>(idxA, verts, V1, V1, NN,
                                               fout1, 64, d1, fm1, 1);
    // pool 8192 -> 2048
    int* idxP1 = (int*)arena7;
    knn_select<32, 5><<<B * V2, 256, 0, stream>>>(verts, qarr, V1, V2, idxP1);
    float* fm1p = arena6;
    pool_max<<<B * V2, 256, 0, stream>>>(idxP1, fm1, V1, V2, 64, fm1p);

    // ---- Stage 2 (V=2048) ----
    int* idxB = arena4;
    knn_select<8, 51><<<B * V2, 256, 0, stream>>>(verts, qarr, V1, V2, idxB);
    float* fout2 = arena3;
    gemm_tiled<<<dim3(B * V2 / 64, 256 / 64), 256, 0, stream>>>(
        fm1p, w2, b2, fout2, B * V2, 64, 256);
    float* fm2 = arena5;
    conv_kernel<128><<<B * V2, 128, 0, stream>>>(idxB, verts, V1, V2, NN,
                                                 fout2, 128, d2, fm2, 1);
    float* fout3 = arena1;
    gemm_tiled<<<dim3(B * V2 / 64, 512 / 64), 256, 0, stream>>>(
        fm2, w3, b3, fout3, B * V2, 128, 512);
    float* fm3 = arena2;
    conv_kernel<256><<<B * V2, 256, 0, stream>>>(idxB, verts, V1, V2, NN,
                                                 fout3, 256, d3, fm3, 1);
    // pool 2048 -> 512
    int* idxP2 = (int*)arena7;
    knn_select<8, 5><<<B * V3, 256, 0, stream>>>(verts, qarr, V1, V3, idxP2);
    float* fm3p = arena6;
    pool_max<<<B * V3, 256, 0, stream>>>(idxP2, fm3, V2, V3, 256, fm3p);

    // ---- Stage 3 (V=512) ----
    int* idxC = arena4;
    knn_select<2, 51><<<B * V3, 256, 0, stream>>>(verts, qarr, V1, V3, idxC);
    float* fout4 = arena1;
    gemm_tiled<<<dim3(B * V3 / 64, 2048 / 64), 256, 0, stream>>>(
        fm3p, w4, b4, fout4, B * V3, 256, 2048);
    float* fm4 = arena2;
    conv_kernel<256><<<B * V3, 256, 0, stream>>>(idxC, verts, V1, V3, NN,
                                                 fout4, 1024, d4, fm4, 0);
    // ---- Head ----
    colmax_part<<<dim3(1024 / 256, B, 8), 256, 0, stream>>>(fm4, V3, 1024, V3 / 8, part);
    fc_kernel<<<B, 256, 0, stream>>>(part, fcw, fcb, (float*)d_out, 8);
}

// Round 5
// 370.979 us; speedup vs baseline: 5.3553x; 1.1603x over previous
//
#include <hip/hip_runtime.h>
#include <cmath>

// ---------------------------------------------------------------------------
// PointCloudFeatureExtractor — full pipeline port (fp32).
// Round 5: estimator-threshold kNN (check M>=SEL, provable fallback),
//          pool reuses first-4 of the 50-NN lists (pool kNN launches removed).
// ---------------------------------------------------------------------------

// q[i] = |v_i|^2 with the exact op order used by the knn distance formula.
__global__ __launch_bounds__(256) void precompute_q(
    const float* __restrict__ v, float* __restrict__ q, int n)
{
#pragma clang fp contract(off)
    const int i = blockIdx.x * 256 + threadIdx.x;
    if (i < n) {
        const float x = v[i * 3 + 0];
        const float y = v[i * 3 + 1];
        const float z = v[i * 3 + 2];
        q[i] = (x * x + y * y) + z * z;
    }
}

// kNN v5: one block (256 threads) per query row; candidates = 256*CPT rows.
//  1) per-thread local min of flipped-u32 distance keys -> hmin[256]
//  2) estimator: wave 0 ranks its 64 minima; T = max{h : strict-rank < EST}
//  3) exhaustive extract of keys <= T.  If M >= SEL the top-SEL are all
//     among the survivors -> exact.  Else (rare) fall back to the provable
//     threshold over all 256 minima (round-4 algorithm) and re-extract.
//  4) exact rank-count over survivors; ranks 1..SEL-1 -> output.
// Distance math is bit-identical to the validated round-1 kernel.
template <int CPT, int SEL, int EST = 20>
__global__ __launch_bounds__(256) void knn_select(
    const float* __restrict__ v, const float* __restrict__ qarr,
    int vStride, int nRows, int* __restrict__ outIdx)
{
#pragma clang fp contract(off)
    const int tid = threadIdx.x;
    const int bi  = blockIdx.x;          // b*nRows + row
    const int b   = bi / nRows;
    const int row = bi % nRows;
    const float* vb = v + (size_t)b * vStride * 3;
    const float* qb = qarr + (size_t)b * vStride;

    const float px = vb[row * 3 + 0];
    const float py = vb[row * 3 + 1];
    const float pz = vb[row * 3 + 2];
    const float qrow = qb[row];

    unsigned ku[CPT];
    unsigned umin = 0xffffffffu;
#pragma unroll
    for (int s = 0; s < CPT; ++s) {
        const int j = tid + (s << 8);
        const float cx = vb[j * 3 + 0];
        const float cy = vb[j * 3 + 1];
        const float cz = vb[j * 3 + 2];
        const float inner = (px * cx + py * cy) + pz * cz;
        const float dist  = ((-2.0f * inner) + qb[j]) + qrow;
        unsigned u = __float_as_uint(dist);
        u = (u & 0x80000000u) ? ~u : (u | 0x80000000u);
        ku[s] = u;
        if (u < umin) umin = u;
    }

    constexpr int CAP = (CPT * SEL > 256) ? CPT * SEL : 256;
    __shared__ unsigned long long buf[CAP];
    __shared__ unsigned hmin[256];
    __shared__ unsigned T_s, T2_s;
    __shared__ int cnt;

    hmin[tid] = umin;
    if (tid == 0) { T_s = 0u; T2_s = 0u; cnt = 0; }
    __syncthreads();

    // estimator threshold from wave 0's 64 minima
    if (tid < 64) {
        int r = 0;
#pragma unroll 8
        for (int i = 0; i < 64; ++i) r += (hmin[i] < umin) ? 1 : 0;
        if (r < EST) atomicMax(&T_s, umin);
    }
    __syncthreads();
    unsigned T = T_s;

#pragma unroll
    for (int s = 0; s < CPT; ++s) {
        if (ku[s] <= T) {
            const int p = atomicAdd(&cnt, 1);
            if (p < CAP)
                buf[p] = (((unsigned long long)ku[s]) << 32)
                       | (unsigned)(tid + (s << 8));
        }
    }
    __syncthreads();
    int M = cnt;

    if (M < SEL || M > CAP) {            // rare: provable fallback (exact)
        int r = 0;
#pragma unroll 8
        for (int i = 0; i < 256; ++i) r += (hmin[i] < umin) ? 1 : 0;
        if (r < SEL) atomicMax(&T2_s, umin);
        if (tid == 0) cnt = 0;
        __syncthreads();
        T = T2_s;                         // >= SEL keys <= T; M2 <= SEL*CPT
#pragma unroll
        for (int s = 0; s < CPT; ++s) {
            if (ku[s] <= T) {
                const int p = atomicAdd(&cnt, 1);
                buf[p] = (((unsigned long long)ku[s]) << 32)
                       | (unsigned)(tid + (s << 8));
            }
        }
        __syncthreads();
        M = cnt;
    }

    for (int s2 = tid; s2 < M; s2 += 256) {
        const unsigned long long k = buf[s2];
        int rr = 0;
        for (int i = 0; i < M; ++i) rr += (buf[i] < k) ? 1 : 0;
        if (rr >= 1 && rr < SEL)
            outIdx[(size_t)bi * (SEL - 1) + (rr - 1)] = (int)(k & 0xffffffffu);
    }
}

// Unified conv: if fout==nullptr this is conv_surface (f_support=1, f_center=0).
template <int NT>
__global__ __launch_bounds__(NT) void conv_kernel(
    const int*   __restrict__ idx,   // (B, V, NN)
    const float* __restrict__ v,     // (B, vStride, 3)
    int vStride, int V, int NN,
    const float* __restrict__ fout,  // (B, V, 2*oc) or nullptr
    int oc,
    const float* __restrict__ dirs,  // (3, oc)
    float* __restrict__ out,         // (B, V, oc)
    int do_relu)
{
#pragma clang fp contract(off)
    __shared__ float dnx[64], dny[64], dnz[64];
    __shared__ int   nb[64];
    const int bi  = blockIdx.x;     // b*V + i
    const int b   = bi / V;
    const int i   = bi % V;
    const int tid = threadIdx.x;

    if (tid < NN) {
        const int j = idx[(size_t)bi * NN + tid];
        nb[tid] = j;
        const float px = v[((size_t)b * vStride + i) * 3 + 0];
        const float py = v[((size_t)b * vStride + i) * 3 + 1];
        const float pz = v[((size_t)b * vStride + i) * 3 + 2];
        const float dx = v[((size_t)b * vStride + j) * 3 + 0] - px;
        const float dy = v[((size_t)b * vStride + j) * 3 + 1] - py;
        const float dz = v[((size_t)b * vStride + j) * 3 + 2] - pz;
        const float n  = sqrtf((dx * dx + dy * dy) + dz * dz);
        const float dn = fmaxf(n, 1e-12f);
        dnx[tid] = dx / dn;
        dny[tid] = dy / dn;
        dnz[tid] = dz / dn;
    }
    __syncthreads();

    for (int c = tid; c < oc; c += NT) {
        float d0 = dirs[c], d1 = dirs[oc + c], d2 = dirs[2 * oc + c];
        const float nd = sqrtf((d0 * d0 + d1 * d1) + d2 * d2);
        const float dc = fmaxf(nd, 1e-12f);
        d0 /= dc; d1 /= dc; d2 /= dc;

        float fcen = 0.f;
        if (fout) fcen = fout[(size_t)bi * (2 * oc) + c];

        float m = -INFINITY;
        for (int n = 0; n < NN; ++n) {
            float th = (dnx[n] * d0 + dny[n] * d1) + dnz[n] * d2;
            th = fmaxf(th, 0.f);
            float fs = 1.f;
            if (fout) fs = fout[((size_t)b * V + nb[n]) * (2 * oc) + oc + c];
            m = fmaxf(m, th * fs);
        }
        float r = fcen + m;
        if (do_relu) r = fmaxf(r, 0.f);
        out[(size_t)bi * oc + c] = r;
    }
}

// out(M,N) = A(M,K) @ W(K,N) + bias(N). 64x64 tile, BK=32, 256 threads,
// 4x4 per thread.
__global__ __launch_bounds__(256) void gemm_tiled(
    const float* __restrict__ A, const float* __restrict__ W,
    const float* __restrict__ bias, float* __restrict__ out,
    int M, int K, int N)
{
    __shared__ float As[32][68];
    __shared__ float Bs[32][64];
    const int tid = threadIdx.x;
    const int tx = tid & 15, ty = tid >> 4;
    const int r0 = blockIdx.x * 64;
    const int c0 = blockIdx.y * 64;

    const float4 bv = *(const float4*)&bias[c0 + tx * 4];
    float acc[4][4];
#pragma unroll
    for (int i = 0; i < 4; ++i) {
        acc[i][0] = bv.x; acc[i][1] = bv.y; acc[i][2] = bv.z; acc[i][3] = bv.w;
    }

    const int rowA = tid >> 2;
    const int ca4  = tid & 3;
    const int rowB = tid >> 4;
    const int cb4  = tid & 15;

    for (int k0 = 0; k0 < K; k0 += 32) {
        const float4 a0 = *(const float4*)&A[(size_t)(r0 + rowA) * K + k0 + ca4 * 4];
        const float4 a1 = *(const float4*)&A[(size_t)(r0 + rowA) * K + k0 + (ca4 + 4) * 4];
        const float4 b0 = *(const float4*)&W[(size_t)(k0 + rowB) * N + c0 + cb4 * 4];
        const float4 b1 = *(const float4*)&W[(size_t)(k0 + rowB + 16) * N + c0 + cb4 * 4];
        __syncthreads();
        As[ca4 * 4 + 0][rowA] = a0.x;
        As[ca4 * 4 + 1][rowA] = a0.y;
        As[ca4 * 4 + 2][rowA] = a0.z;
        As[ca4 * 4 + 3][rowA] = a0.w;
        As[ca4 * 4 + 16][rowA] = a1.x;
        As[ca4 * 4 + 17][rowA] = a1.y;
        As[ca4 * 4 + 18][rowA] = a1.z;
        As[ca4 * 4 + 19][rowA] = a1.w;
        *(float4*)&Bs[rowB][cb4 * 4]      = b0;
        *(float4*)&Bs[rowB + 16][cb4 * 4] = b1;
        __syncthreads();
#pragma unroll
        for (int kk = 0; kk < 32; ++kk) {
            const float4 av = *(const float4*)&As[kk][ty * 4];
            const float4 wv = *(const float4*)&Bs[kk][tx * 4];
            acc[0][0] += av.x * wv.x; acc[0][1] += av.x * wv.y;
            acc[0][2] += av.x * wv.z; acc[0][3] += av.x * wv.w;
            acc[1][0] += av.y * wv.x; acc[1][1] += av.y * wv.y;
            acc[1][2] += av.y * wv.z; acc[1][3] += av.y * wv.w;
            acc[2][0] += av.z * wv.x; acc[2][1] += av.z * wv.y;
            acc[2][2] += av.z * wv.z; acc[2][3] += av.z * wv.w;
            acc[3][0] += av.w * wv.x; acc[3][1] += av.w * wv.y;
            acc[3][2] += av.w * wv.z; acc[3][3] += av.w * wv.w;
        }
    }
#pragma unroll
    for (int i = 0; i < 4; ++i) {
        float4 o;
        o.x = acc[i][0]; o.y = acc[i][1]; o.z = acc[i][2]; o.w = acc[i][3];
        *(float4*)&out[(size_t)(r0 + ty * 4 + i) * N + c0 + tx * 4] = o;
    }
}

// pooled[b,i,c] = max over the first 4 entries of the 50-NN row of vertex i.
__global__ __launch_bounds__(256) void pool_max(
    const int* __restrict__ idxNN, int nnStride, const float* __restrict__ fm,
    int Vin, int pn, int C, float* __restrict__ out)
{
    const int bi  = blockIdx.x;      // b*pn + i
    const int b   = bi / pn;
    const int i   = bi % pn;
    const int tid = threadIdx.x;
    const int* r = idxNN + (size_t)(b * Vin + i) * nnStride;
    const int j0 = r[0], j1 = r[1], j2 = r[2], j3 = r[3];
    for (int c = tid; c < C; c += 256) {
        float m = fm[((size_t)b * Vin + j0) * C + c];
        m = fmaxf(m, fm[((size_t)b * Vin + j1) * C + c]);
        m = fmaxf(m, fm[((size_t)b * Vin + j2) * C + c]);
        m = fmaxf(m, fm[((size_t)b * Vin + j3) * C + c]);
        out[(size_t)bi * C + c] = m;
    }
}

// partial column max over a chunk of rows. grid (C/256, B, nChunk).
__global__ __launch_bounds__(256) void colmax_part(
    const float* __restrict__ fm, int V, int C, int rowsPerChunk,
    float* __restrict__ part)
{
    const int b = blockIdx.y, chunk = blockIdx.z;
    const int nChunk = gridDim.z;
    const int c = blockIdx.x * 256 + threadIdx.x;
    const int i0 = chunk * rowsPerChunk;
    float m = -INFINITY;
    for (int i = i0; i < i0 + rowsPerChunk; ++i)
        m = fmaxf(m, fm[((size_t)b * V + i) * C + c]);
    part[((size_t)b * nChunk + chunk) * C + c] = m;
}

// out[b, :256] = (max-merge of partials)[b, :1024] @ W(1024,256) + bias
__global__ __launch_bounds__(256) void fc_kernel(
    const float* __restrict__ part, const float* __restrict__ W,
    const float* __restrict__ bias, float* __restrict__ out, int nChunk)
{
    __shared__ float f[1024];
    const int b = blockIdx.x, tid = threadIdx.x;
    for (int k = tid; k < 1024; k += 256) {
        float m = part[((size_t)b * nChunk) * 1024 + k];
        for (int ch = 1; ch < nChunk; ++ch)
            m = fmaxf(m, part[((size_t)b * nChunk + ch) * 1024 + k]);
        f[k] = m;
    }
    __syncthreads();
    float acc = bias[tid];
    for (int k = 0; k < 1024; ++k) acc += f[k] * W[(size_t)k * 256 + tid];
    out[(size_t)b * 256 + tid] = acc;
}

extern "C" void kernel_launch(void* const* d_in, const int* in_sizes, int n_in,
                              void* d_out, int out_size, void* d_ws, size_t ws_size,
                              hipStream_t stream) {
    const float* verts = (const float*)d_in[0];
    const float* dir0  = (const float*)d_in[1];
    const float* w1 = (const float*)d_in[2];
    const float* b1 = (const float*)d_in[3];
    const float* d1 = (const float*)d_in[4];
    const float* w2 = (const float*)d_in[5];
    const float* b2 = (const float*)d_in[6];
    const float* d2 = (const float*)d_in[7];
    const float* w3 = (const float*)d_in[8];
    const float* b3 = (const float*)d_in[9];
    const float* d3 = (const float*)d_in[10];
    const float* w4 = (const float*)d_in[11];
    const float* b4 = (const float*)d_in[12];
    const float* d4 = (const float*)d_in[13];
    const float* fcw = (const float*)d_in[14];
    const float* fcb = (const float*)d_in[15];

    const int B = 2, V1 = 8192, V2 = 2048, V3 = 512, NN = 50;

    char* ws = (char*)d_ws;
    float* arena1 = (float*)(ws + 0);          //  8,388,608 : fout1 / fout3 / fout4
    float* arena2 = (float*)(ws + 8388608);    //  4,194,304 : fm1 / fm3 / fm4
    float* arena3 = (float*)(ws + 12582912);   //  4,194,304 : fout2
    int*   arena4 = (int*)  (ws + 16777216);   //  3,276,800 : idxA / idxB / idxC
    float* arena5 = (float*)(ws + 20054016);   //  2,097,152 : fm0 / fm2
    float* arena6 = (float*)(ws + 22151168);   //  1,048,576 : fm1p / fm3p
    float* part   = (float*)(ws + 23265280);   //     65,536 : colmax partials
    float* qarr   = (float*)(ws + 23330816);   //     65,536 : |v|^2 per point

    precompute_q<<<(B * V1 + 255) / 256, 256, 0, stream>>>(verts, qarr, B * V1);

    // ---- Stage 1 (V=8192) ----
    int* idxA = arena4;
    knn_select<32, 51><<<B * V1, 256, 0, stream>>>(verts, qarr, V1, V1, idxA);

    float* fm0 = arena5;
    conv_kernel<64><<<B * V1, 64, 0, stream>>>(idxA, verts, V1, V1, NN,
                                               nullptr, 32, dir0, fm0, 1);
    float* fout1 = arena1;
    gemm_tiled<<<dim3(B * V1 / 64, 128 / 64), 256, 0, stream>>>(
        fm0, w1, b1, fout1, B * V1, 32, 128);
    float* fm1 = arena2;
    conv_kernel<64><<<B * V1, 64, 0, stream>>>(idxA, verts, V1, V1, NN,
                                               fout1, 64, d1, fm1, 1);
    // pool 8192 -> 2048 : 4-NN = first 4 of the 50-NN rows
    float* fm1p = arena6;
    pool_max<<<B * V2, 256, 0, stream>>>(idxA, NN, fm1, V1, V2, 64, fm1p);

    // ---- Stage 2 (V=2048) ----
    int* idxB = arena4;
    knn_select<8, 51><<<B * V2, 256, 0, stream>>>(verts, qarr, V1, V2, idxB);
    float* fout2 = arena3;
    gemm_tiled<<<dim3(B * V2 / 64, 256 / 64), 256, 0, stream>>>(
        fm1p, w2, b2, fout2, B * V2, 64, 256);
    float* fm2 = arena5;
    conv_kernel<128><<<B * V2, 128, 0, stream>>>(idxB, verts, V1, V2, NN,
                                                 fout2, 128, d2, fm2, 1);
    float* fout3 = arena1;
    gemm_tiled<<<dim3(B * V2 / 64, 512 / 64), 256, 0, stream>>>(
        fm2, w3, b3, fout3, B * V2, 128, 512);
    float* fm3 = arena2;
    conv_kernel<256><<<B * V2, 256, 0, stream>>>(idxB, verts, V1, V2, NN,
                                                 fout3, 256, d3, fm3, 1);
    // pool 2048 -> 512 : 4-NN = first 4 of the 50-NN rows
    float* fm3p = arena6;
    pool_max<<<B * V3, 256, 0, stream>>>(idxB, NN, fm3, V2, V3, 256, fm3p);

    // ---- Stage 3 (V=512) ----
    int* idxC = arena4;
    knn_select<2, 51><<<B * V3, 256, 0, stream>>>(verts, qarr, V1, V3, idxC);
    float* fout4 = arena1;
    gemm_tiled<<<dim3(B * V3 / 64, 2048 / 64), 256, 0, stream>>>(
        fm3p, w4, b4, fout4, B * V3, 256, 2048);
    float* fm4 = arena2;
    conv_kernel<256><<<B * V3, 256, 0, stream>>>(idxC, verts, V1, V3, NN,
                                                 fout4, 1024, d4, fm4, 0);
    // ---- Head ----
    colmax_part<<<dim3(1024 / 256, B, 8), 256, 0, stream>>>(fm4, V3, 1024, V3 / 8, part);
    fc_kernel<<<B, 256, 0, stream>>>(part, fcw, fcb, (float*)d_out, 8);
}